// Round 6
// baseline (232.574 us; speedup 1.0000x reference)
//
#include <hip/hip_runtime.h>

typedef unsigned short u16;
typedef __bf16 bf16x8 __attribute__((ext_vector_type(8)));
typedef float f32x4 __attribute__((ext_vector_type(4)));
typedef float f32x16 __attribute__((ext_vector_type(16)));

#define DIMD 512
#define SEQN 2048
#define NB   8
#define NH   8
#define DH   64
#define BHN  (NB*NH)          // 64
#define MROWS (NB*SEQN)       // 16384
#define QSCALE 0.18033688f    // 0.125 * log2(e)

__device__ __forceinline__ u16 f2bf(float f) {   // full RNE (staging only)
  union { float f; unsigned u; } x; x.f = f;
  unsigned r = x.u + 0x7fffu + ((x.u >> 16) & 1u);
  return (u16)(r >> 16);
}

// 16B global -> LDS DMA. lbase is wave-uniform; HW lands lane i at lbase+i*16.
__device__ __forceinline__ void gll16(const u16* g, u16* lbase) {
#if __has_builtin(__builtin_amdgcn_global_load_lds)
  __builtin_amdgcn_global_load_lds(
      (const __attribute__((address_space(1))) unsigned int*)g,
      (__attribute__((address_space(3))) unsigned int*)lbase, 16, 0, 0);
#else
  *(uint4*)((u16*)lbase + (threadIdx.x & 63) * 8) = *(const uint4*)g;
#endif
}

// P-fragment builder: 8 f32 (keys {0,1,2,3,8,9,10,11}+4*hi of a 32-key tile)
// -> bf16x8 B-fragment dwords [m0,m1,m2,m3] via cvt_pk + permlane32_swap.
// swap semantics: a' = {a.lo, b.lo}, b' = {a.hi, b.hi}.  (verified round 3)
__device__ __forceinline__ bf16x8 mkfrag(float e0, float e1, float e2, float e3,
                                          float e4, float e5, float e6, float e7) {
  unsigned a0, a1, a2, a3;
  asm("v_cvt_pk_bf16_f32 %0, %1, %2" : "=v"(a0) : "v"(e0), "v"(e1));
  asm("v_cvt_pk_bf16_f32 %0, %1, %2" : "=v"(a1) : "v"(e2), "v"(e3));
  asm("v_cvt_pk_bf16_f32 %0, %1, %2" : "=v"(a2) : "v"(e4), "v"(e5));
  asm("v_cvt_pk_bf16_f32 %0, %1, %2" : "=v"(a3) : "v"(e6), "v"(e7));
  asm volatile("v_permlane32_swap_b32 %0, %1" : "+v"(a0), "+v"(a2));
  asm volatile("v_permlane32_swap_b32 %0, %1" : "+v"(a1), "+v"(a3));
  union { unsigned u[4]; bf16x8 v; } r;
  r.u[0] = a0; r.u[1] = a1; r.u[2] = a2; r.u[3] = a3;
  return r.v;
}

// ---------------- weight fp32 -> bf16 pre-conversion (both weights) --------
__global__ __launch_bounds__(256) void wcvt2(
    const float* __restrict__ wa, const float* __restrict__ wb,
    u16* __restrict__ oa, u16* __restrict__ ob, int na, int nb) {
  int i = (blockIdx.x * 256 + threadIdx.x) * 8;
  const float* src; u16* dst; int idx;
  if (i < na) { src = wa; dst = oa; idx = i; }
  else { idx = i - na; if (idx >= nb) return; src = wb; dst = ob; }
  float4 f0 = *(const float4*)(src + idx);
  float4 f1 = *(const float4*)(src + idx + 4);
  union { uint4 v; u16 s[8]; } u;
  u.s[0] = f2bf(f0.x); u.s[1] = f2bf(f0.y); u.s[2] = f2bf(f0.z); u.s[3] = f2bf(f0.w);
  u.s[4] = f2bf(f1.x); u.s[5] = f2bf(f1.y); u.s[6] = f2bf(f1.z); u.s[7] = f2bf(f1.w);
  *(uint4*)(dst + idx) = u.v;
}

// ---------------- LayerNorm: one wave per row of 512. fp32 in -> bf16 out --
__global__ __launch_bounds__(256) void ln_kernel(
    const float* __restrict__ x, const float* __restrict__ gamma,
    const float* __restrict__ beta, u16* __restrict__ xn) {
  int row = blockIdx.x * 4 + (threadIdx.x >> 6);
  int lane = threadIdx.x & 63;
  const float* xr = x + (size_t)row * DIMD;
  float f[8], g[8], b[8];
  *(float4*)&f[0] = *(const float4*)(xr + lane * 8);
  *(float4*)&f[4] = *(const float4*)(xr + lane * 8 + 4);
  *(float4*)&g[0] = *(const float4*)(gamma + lane * 8);
  *(float4*)&g[4] = *(const float4*)(gamma + lane * 8 + 4);
  *(float4*)&b[0] = *(const float4*)(beta + lane * 8);
  *(float4*)&b[4] = *(const float4*)(beta + lane * 8 + 4);
  float sum = 0.f, sq = 0.f;
#pragma unroll
  for (int i = 0; i < 8; ++i) { sum += f[i]; sq += f[i] * f[i]; }
#pragma unroll
  for (int off = 1; off < 64; off <<= 1) {
    sum += __shfl_xor(sum, off, 64);
    sq  += __shfl_xor(sq, off, 64);
  }
  float mean = sum * (1.0f / DIMD);
  float var = sq * (1.0f / DIMD) - mean * mean;
  float rstd = rsqrtf(var + 1e-6f);
  union { uint4 v; u16 s[8]; } uo;
#pragma unroll
  for (int i = 0; i < 8; ++i)
    uo.s[i] = f2bf((f[i] - mean) * rstd * g[i] + b[i]);
  *(uint4*)(xn + (size_t)row * DIMD + lane * 8) = uo.v;
}

// ------- QKV GEMM v2: 128x256 tile, 512 thr (8 waves 2Mx4N), XCD swizzle ---
// A-tile staged once serves 256 output cols (A HBM traffic halved vs 128x128);
// grid linearized bm-major so same-A-panel blocks land in one XCD's L2.
// part = bn>>1 block-uniform: 0->q (scaled), 1->k, 2->v^T (b64-packed).
__global__ __launch_bounds__(512) void qkv_gemm(
    const u16* __restrict__ A, const u16* __restrict__ Bm,
    u16* __restrict__ qo, u16* __restrict__ ko, u16* __restrict__ vto) {
  __shared__ __align__(16) u16 la[128 * 64];   // 16 KB
  __shared__ __align__(16) u16 lb[256 * 64];   // 32 KB
  const int K = DIMD;
  int tid = threadIdx.x;
  // bijective XCD-chunk swizzle: nwg=768, cpx=96; then bm-major decode
  int swz = (blockIdx.x & 7) * 96 + (blockIdx.x >> 3);
  int bm = swz / 6, bn = swz % 6;
  int wid = tid >> 6, lane = tid & 63, lm = lane & 15, quad = lane >> 4;
  int wm = wid >> 2, wn = wid & 3;      // 2 x 4 wave grid
  int lsw = lm & 7;
  int part = bn >> 1;  // block-uniform
  f32x4 acc[4][4] = {};
  const u16* Ab = A + (size_t)(bm * 128) * K;
  const u16* Bb = Bm + (size_t)(bn * 256) * K;
  int cb_row = lane >> 3, cb_sub = lane & 7;
  int xsrc = (cb_sub ^ cb_row) * 8;   // swizzled source chunk offset
  for (int k0 = 0; k0 < K; k0 += 64) {
    __syncthreads();
#pragma unroll
    for (int r = 0; r < 2; ++r) {     // A: 16 segs over 8 waves
      int seg = wid * 2 + r;
      int row = seg * 8 + cb_row;
      gll16(Ab + (size_t)row * K + k0 + xsrc, &la[seg * 512]);
    }
#pragma unroll
    for (int r = 0; r < 4; ++r) {     // B: 32 segs over 8 waves
      int seg = wid * 4 + r;
      int row = seg * 8 + cb_row;
      gll16(Bb + (size_t)row * K + k0 + xsrc, &lb[seg * 512]);
    }
    __syncthreads();
#pragma unroll
    for (int h = 0; h < 2; ++h) {
      bf16x8 af[4], bfr[4];
#pragma unroll
      for (int i = 0; i < 4; ++i)
        af[i] = *(const bf16x8*)&la[(wm * 64 + i * 16 + lm) * 64 + (((h * 4 + quad) ^ lsw) * 8)];
#pragma unroll
      for (int j = 0; j < 4; ++j)
        bfr[j] = *(const bf16x8*)&lb[(wn * 64 + j * 16 + lm) * 64 + (((h * 4 + quad) ^ lsw) * 8)];
      if (part == 2) {
#pragma unroll
        for (int i = 0; i < 4; ++i)
#pragma unroll
          for (int j = 0; j < 4; ++j)
            acc[i][j] = __builtin_amdgcn_mfma_f32_16x16x32_bf16(af[i], bfr[j], acc[i][j], 0, 0, 0);
      } else {
        // swapped operands: acc regs hold 4 consecutive output cols
#pragma unroll
        for (int i = 0; i < 4; ++i)
#pragma unroll
          for (int j = 0; j < 4; ++j)
            acc[i][j] = __builtin_amdgcn_mfma_f32_16x16x32_bf16(bfr[j], af[i], acc[i][j], 0, 0, 0);
      }
    }
  }
  if (part == 2) {
#pragma unroll
    for (int i = 0; i < 4; ++i)
#pragma unroll
      for (int j = 0; j < 4; ++j) {
        int col = bn * 256 + wn * 64 + j * 16 + lm;
        int rem = col & 511, h = rem >> 6, d = rem & 63;
        int rg = bm * 128 + wm * 64 + i * 16 + quad * 4;
        int b = rg >> 11, nn = rg & 2047;
        union { unsigned long long ll; u16 s4[4]; } pk;
#pragma unroll
        for (int r = 0; r < 4; ++r) pk.s4[r] = f2bf(acc[i][j][r]);
        *(unsigned long long*)&vto[((size_t)(b * NH + h) * DH + d) * SEQN + nn] = pk.ll;
      }
  } else {
    u16* dst = part ? ko : qo;
    float sc = part ? 1.0f : QSCALE;
#pragma unroll
    for (int i = 0; i < 4; ++i)
#pragma unroll
      for (int j = 0; j < 4; ++j) {
        int rg = bm * 128 + wm * 64 + i * 16 + lm;   // token row
        int b = rg >> 11, nn = rg & 2047;
        int col = bn * 256 + wn * 64 + j * 16 + quad * 4;  // 4 consecutive cols
        int rem = col & 511, hh = rem >> 6, d = rem & 63;
        union { unsigned long long ll; __bf16 h4[4]; } pk;
#pragma unroll
        for (int r = 0; r < 4; ++r) pk.h4[r] = (__bf16)(acc[i][j][r] * sc);
        *(unsigned long long*)&dst[((size_t)(b * NH + hh) * SEQN + nn) * DH + d] = pk.ll;
      }
  }
}

// -------- Flash attention v10 (round-4 best, verbatim): 64 Q-rows/wave -----
__global__ __launch_bounds__(256, 2) void attn_kernel(
    const u16* __restrict__ q, const u16* __restrict__ k,
    const u16* __restrict__ vt, u16* __restrict__ att) {
  __shared__ __align__(16) u16 kt[2][64 * 64];    // 2 x 8 KB, chunk-swizzled
  __shared__ __align__(16) u16 vtt[2][64 * 64];   // 2 x 8 KB, chunk-swizzled
  int bh = blockIdx.x;
  int wid = threadIdx.x >> 6, lane = threadIdx.x & 63;
  int l31 = lane & 31, hi = lane >> 5;
  int qrow0 = blockIdx.y * 256 + wid * 64;
  const u16* qb = q + (size_t)bh * SEQN * DH;
  const u16* kb = k + (size_t)bh * SEQN * DH;
  const u16* vb = vt + (size_t)bh * DH * SEQN;

  int cb_row = lane >> 3, cb_sub = lane & 7;
  int xstage = (cb_sub ^ cb_row) * 8;

  // Q B-fragments: lane holds Q[qrow][d = c*16 + hi*8 + j], c=0..3
  bf16x8 qfA[4], qfB[4];
#pragma unroll
  for (int c = 0; c < 4; ++c) {
    qfA[c] = *(const bf16x8*)(qb + (size_t)(qrow0 + l31) * DH + c * 16 + hi * 8);
    qfB[c] = *(const bf16x8*)(qb + (size_t)(qrow0 + 32 + l31) * DH + c * 16 + hi * 8);
  }

  f32x16 OtA0 = {}, OtA1 = {}, OtB0 = {}, OtB1 = {};
  float lA = 0.f, lB = 0.f;   // per-lane half-sums (keys with bit2 == hi)

  auto stage = [&](int bsel, int j0) {
    if (wid < 2) {
#pragma unroll
      for (int i = 0; i < 4; ++i) {
        int seg = wid * 4 + i;
        int row = seg * 8 + cb_row;
        gll16(kb + (size_t)(j0 + row) * DH + xstage, &kt[bsel][seg * 512]);
      }
    } else {
#pragma unroll
      for (int i = 0; i < 4; ++i) {
        int seg = (wid - 2) * 4 + i;
        int row = seg * 8 + cb_row;   // row = d index
        gll16(vb + (size_t)row * SEQN + j0 + xstage, &vtt[bsel][seg * 512]);
      }
    }
  };

  stage(0, 0);
  for (int t = 0; t < SEQN / 64; ++t) {
    int bsel = t & 1;
    __syncthreads();   // drains stage(bsel) [issued last iter] + orders LDS
    if (t + 1 < SEQN / 64) stage(bsel ^ 1, (t + 1) * 64);

    bf16x8 pbA[4], pbB[4];   // PV B-fragments, kv blocks 0..3 (16 kv each)
    int rsw = l31 & 7;
#pragma unroll
    for (int tb = 0; tb < 2; ++tb) {   // two 32-key tiles
      int row = tb * 32 + l31;
      f32x16 zA = {}, zB = {};
      __builtin_amdgcn_s_setprio(1);
#pragma unroll
      for (int c = 0; c < 4; ++c) {
        bf16x8 kf = *(const bf16x8*)&kt[bsel][row * 64 + (((2 * c + hi) ^ rsw) * 8)];
        zA = __builtin_amdgcn_mfma_f32_32x32x16_bf16(kf, qfA[c], zA, 0, 0, 0);
        zB = __builtin_amdgcn_mfma_f32_32x32x16_bf16(kf, qfB[c], zB, 0, 0, 0);
      }
      __builtin_amdgcn_s_setprio(0);
      float eA[16], eB[16];
#pragma unroll
      for (int r = 0; r < 16; ++r) {
        eA[r] = __builtin_amdgcn_exp2f(zA[r]); lA += eA[r];
        eB[r] = __builtin_amdgcn_exp2f(zB[r]); lB += eB[r];
      }
      pbA[tb * 2 + 0] = mkfrag(eA[0], eA[1], eA[2], eA[3], eA[4], eA[5], eA[6], eA[7]);
      pbA[tb * 2 + 1] = mkfrag(eA[8], eA[9], eA[10], eA[11], eA[12], eA[13], eA[14], eA[15]);
      pbB[tb * 2 + 0] = mkfrag(eB[0], eB[1], eB[2], eB[3], eB[4], eB[5], eB[6], eB[7]);
      pbB[tb * 2 + 1] = mkfrag(eB[8], eB[9], eB[10], eB[11], eB[12], eB[13], eB[14], eB[15]);
    }
    // PV: O[d][qrow] += V^T[d][kv] P[kv][qrow]; each va feeds 4 MFMAs
#pragma unroll
    for (int c = 0; c < 4; ++c) {
      bf16x8 va0 = *(const bf16x8*)&vtt[bsel][l31 * 64 + (((2 * c + hi) ^ rsw) * 8)];
      bf16x8 va1 = *(const bf16x8*)&vtt[bsel][(32 + l31) * 64 + (((2 * c + hi) ^ rsw) * 8)];
      __builtin_amdgcn_s_setprio(1);
      OtA0 = __builtin_amdgcn_mfma_f32_32x32x16_bf16(va0, pbA[c], OtA0, 0, 0, 0);
      OtA1 = __builtin_amdgcn_mfma_f32_32x32x16_bf16(va1, pbA[c], OtA1, 0, 0, 0);
      OtB0 = __builtin_amdgcn_mfma_f32_32x32x16_bf16(va0, pbB[c], OtB0, 0, 0, 0);
      OtB1 = __builtin_amdgcn_mfma_f32_32x32x16_bf16(va1, pbB[c], OtB1, 0, 0, 0);
      __builtin_amdgcn_s_setprio(0);
    }
  }
  int b = bh >> 3, h = bh & 7;
  float lAf = lA + __shfl_xor(lA, 32, 64);
  float lBf = lB + __shfl_xor(lB, 32, 64);
  float invA = __builtin_amdgcn_rcpf(lAf);
  float invB = __builtin_amdgcn_rcpf(lBf);
  size_t rowA = ((size_t)(b * SEQN + qrow0 + l31)) * DIMD + h * DH;
  size_t rowB = ((size_t)(b * SEQN + qrow0 + 32 + l31)) * DIMD + h * DH;
#pragma unroll
  for (int rb = 0; rb < 4; ++rb) {
    union { unsigned long long ll; __bf16 h4[4]; } a0, a1, b0, b1;
#pragma unroll
    for (int rr = 0; rr < 4; ++rr) {
      a0.h4[rr] = (__bf16)(OtA0[rb * 4 + rr] * invA);
      a1.h4[rr] = (__bf16)(OtA1[rb * 4 + rr] * invA);
      b0.h4[rr] = (__bf16)(OtB0[rb * 4 + rr] * invB);
      b1.h4[rr] = (__bf16)(OtB1[rb * 4 + rr] * invB);
    }
    *(unsigned long long*)&att[rowA + rb * 8 + hi * 4] = a0.ll;
    *(unsigned long long*)&att[rowA + 32 + rb * 8 + hi * 4] = a1.ll;
    *(unsigned long long*)&att[rowB + rb * 8 + hi * 4] = b0.ll;
    *(unsigned long long*)&att[rowB + 32 + rb * 8 + hi * 4] = b1.ll;
  }
}

// ------- Proj GEMM + bias: BK=64, swapped operands, XCD swizzle ------------
__global__ __launch_bounds__(256) void proj_gemm(
    const u16* __restrict__ A, const u16* __restrict__ Bm,
    const float* __restrict__ bias, float* __restrict__ C) {
  __shared__ __align__(16) u16 la[128 * 64];
  __shared__ __align__(16) u16 lb[128 * 64];
  const int K = DIMD, N = DIMD;
  int tid = threadIdx.x;
  // bijective XCD-chunk swizzle: nwg=512, cpx=64; bm-major decode
  int swz = (blockIdx.x & 7) * 64 + (blockIdx.x >> 3);
  int bm = swz >> 2, bn = swz & 3;
  int wid = tid >> 6, lane = tid & 63, lm = lane & 15, quad = lane >> 4;
  int wm = wid >> 1, wn = wid & 1;
  int lsw = lm & 7;
  f32x4 acc[4][4] = {};
  const u16* Ab = A + (size_t)(bm * 128) * K;
  const u16* Bb = Bm + (size_t)(bn * 128) * K;
  int cb_row = lane >> 3, cb_sub = lane & 7;
  int xsrc = (cb_sub ^ cb_row) * 8;
  for (int k0 = 0; k0 < K; k0 += 64) {
    __syncthreads();
#pragma unroll
    for (int r = 0; r < 4; ++r) {
      int seg = wid * 4 + r;
      int row = seg * 8 + cb_row;
      size_t goff = (size_t)row * K + k0 + xsrc;
      gll16(Ab + goff, &la[seg * 512]);
      gll16(Bb + goff, &lb[seg * 512]);
    }
    __syncthreads();
#pragma unroll
    for (int h = 0; h < 2; ++h) {
      bf16x8 af[4], bfr[4];
#pragma unroll
      for (int i = 0; i < 4; ++i)
        af[i] = *(const bf16x8*)&la[(wm * 64 + i * 16 + lm) * 64 + (((h * 4 + quad) ^ lsw) * 8)];
#pragma unroll
      for (int j = 0; j < 4; ++j)
        bfr[j] = *(const bf16x8*)&lb[(wn * 64 + j * 16 + lm) * 64 + (((h * 4 + quad) ^ lsw) * 8)];
#pragma unroll
      for (int i = 0; i < 4; ++i)
#pragma unroll
        for (int j = 0; j < 4; ++j)
          acc[i][j] = __builtin_amdgcn_mfma_f32_16x16x32_bf16(bfr[j], af[i], acc[i][j], 0, 0, 0);
    }
  }
#pragma unroll
  for (int i = 0; i < 4; ++i)
#pragma unroll
    for (int j = 0; j < 4; ++j) {
      int rg = bm * 128 + wm * 64 + i * 16 + lm;           // row
      int col = bn * 128 + wn * 64 + j * 16 + quad * 4;    // 4 consecutive cols
      float4 bv = *(const float4*)(bias + col);
      float4 o;
      o.x = acc[i][j][0] + bv.x; o.y = acc[i][j][1] + bv.y;
      o.z = acc[i][j][2] + bv.z; o.w = acc[i][j][3] + bv.w;
      *(float4*)&C[(size_t)rg * N + col] = o;
    }
}

extern "C" void kernel_launch(void* const* d_in, const int* in_sizes, int n_in,
                              void* d_out, int out_size, void* d_ws, size_t ws_size,
                              hipStream_t stream) {
  const float* x      = (const float*)d_in[0];
  const float* w_qkv  = (const float*)d_in[1];
  const float* w_proj = (const float*)d_in[2];
  const float* b_proj = (const float*)d_in[3];
  const float* gamma  = (const float*)d_in[4];
  const float* beta   = (const float*)d_in[5];
  float* out = (float*)d_out;

  const size_t SZ = (size_t)MROWS * DIMD;  // 8388608 elements
  u16* xn  = (u16*)d_ws;
  u16* q   = xn + SZ;
  u16* kk  = q + SZ;
  u16* vt  = kk + SZ;
  u16* wqb = vt + SZ;                        // 786432 elems bf16
  u16* wpb = wqb + (size_t)3 * DIMD * DIMD;  // 262144 elems bf16
  u16* att = xn;  // reuse: xn dead after qkv_gemm

  const int NQKV = 3 * DIMD * DIMD;   // 786432
  const int NPRJ = DIMD * DIMD;       // 262144
  wcvt2<<<dim3((NQKV + NPRJ) / 2048), dim3(256), 0, stream>>>(
      w_qkv, w_proj, wqb, wpb, NQKV, NPRJ);
  ln_kernel<<<dim3(MROWS / 4), dim3(256), 0, stream>>>(x, gamma, beta, xn);
  qkv_gemm<<<dim3((MROWS / 128) * (3 * DIMD / 256)), dim3(512), 0, stream>>>(
      xn, wqb, q, kk, vt);
  attn_kernel<<<dim3(BHN, SEQN / 256), dim3(256), 0, stream>>>(q, kk, vt, att);
  proj_gemm<<<dim3((MROWS / 128) * (DIMD / 128)), dim3(256), 0, stream>>>(
      att, wpb, b_proj, out);
}

// Round 7
// 218.130 us; speedup vs baseline: 1.0662x; 1.0662x over previous
//
#include <hip/hip_runtime.h>

typedef unsigned short u16;
typedef __bf16 bf16x8 __attribute__((ext_vector_type(8)));
typedef float f32x4 __attribute__((ext_vector_type(4)));
typedef float f32x16 __attribute__((ext_vector_type(16)));

#define DIMD 512
#define SEQN 2048
#define NB   8
#define NH   8
#define DH   64
#define BHN  (NB*NH)          // 64
#define MROWS (NB*SEQN)       // 16384
#define QSCALE 0.18033688f    // 0.125 * log2(e)

__device__ __forceinline__ u16 f2bf(float f) {   // full RNE (staging only)
  union { float f; unsigned u; } x; x.f = f;
  unsigned r = x.u + 0x7fffu + ((x.u >> 16) & 1u);
  return (u16)(r >> 16);
}

// 16B global -> LDS DMA. lbase is wave-uniform; HW lands lane i at lbase+i*16.
__device__ __forceinline__ void gll16(const u16* g, u16* lbase) {
#if __has_builtin(__builtin_amdgcn_global_load_lds)
  __builtin_amdgcn_global_load_lds(
      (const __attribute__((address_space(1))) unsigned int*)g,
      (__attribute__((address_space(3))) unsigned int*)lbase, 16, 0, 0);
#else
  *(uint4*)((u16*)lbase + (threadIdx.x & 63) * 8) = *(const uint4*)g;
#endif
}

// P-fragment builder: 8 f32 -> bf16x8 B-fragment via cvt_pk + permlane32_swap
// (verified round 3). swap: a' = {a.lo, b.lo}, b' = {a.hi, b.hi}.
__device__ __forceinline__ bf16x8 mkfrag(float e0, float e1, float e2, float e3,
                                          float e4, float e5, float e6, float e7) {
  unsigned a0, a1, a2, a3;
  asm("v_cvt_pk_bf16_f32 %0, %1, %2" : "=v"(a0) : "v"(e0), "v"(e1));
  asm("v_cvt_pk_bf16_f32 %0, %1, %2" : "=v"(a1) : "v"(e2), "v"(e3));
  asm("v_cvt_pk_bf16_f32 %0, %1, %2" : "=v"(a2) : "v"(e4), "v"(e5));
  asm("v_cvt_pk_bf16_f32 %0, %1, %2" : "=v"(a3) : "v"(e6), "v"(e7));
  asm volatile("v_permlane32_swap_b32 %0, %1" : "+v"(a0), "+v"(a2));
  asm volatile("v_permlane32_swap_b32 %0, %1" : "+v"(a1), "+v"(a3));
  union { unsigned u[4]; bf16x8 v; } r;
  r.u[0] = a0; r.u[1] = a1; r.u[2] = a2; r.u[3] = a3;
  return r.v;
}

#define WAITV(N) asm volatile("s_waitcnt vmcnt(" #N ")" ::: "memory")
#define BARRIER() do { asm volatile("" ::: "memory"); \
                       __builtin_amdgcn_s_barrier();  \
                       asm volatile("" ::: "memory"); } while (0)

// ---------------- weight fp32 -> bf16 pre-conversion (both weights) --------
__global__ __launch_bounds__(256) void wcvt2(
    const float* __restrict__ wa, const float* __restrict__ wb,
    u16* __restrict__ oa, u16* __restrict__ ob, int na, int nb) {
  int i = (blockIdx.x * 256 + threadIdx.x) * 8;
  const float* src; u16* dst; int idx;
  if (i < na) { src = wa; dst = oa; idx = i; }
  else { idx = i - na; if (idx >= nb) return; src = wb; dst = ob; }
  float4 f0 = *(const float4*)(src + idx);
  float4 f1 = *(const float4*)(src + idx + 4);
  union { uint4 v; u16 s[8]; } u;
  u.s[0] = f2bf(f0.x); u.s[1] = f2bf(f0.y); u.s[2] = f2bf(f0.z); u.s[3] = f2bf(f0.w);
  u.s[4] = f2bf(f1.x); u.s[5] = f2bf(f1.y); u.s[6] = f2bf(f1.z); u.s[7] = f2bf(f1.w);
  *(uint4*)(dst + idx) = u.v;
}

// ---------------- LayerNorm: one wave per row of 512. fp32 in -> bf16 out --
__global__ __launch_bounds__(256) void ln_kernel(
    const float* __restrict__ x, const float* __restrict__ gamma,
    const float* __restrict__ beta, u16* __restrict__ xn) {
  int row = blockIdx.x * 4 + (threadIdx.x >> 6);
  int lane = threadIdx.x & 63;
  const float* xr = x + (size_t)row * DIMD;
  float f[8], g[8], b[8];
  *(float4*)&f[0] = *(const float4*)(xr + lane * 8);
  *(float4*)&f[4] = *(const float4*)(xr + lane * 8 + 4);
  *(float4*)&g[0] = *(const float4*)(gamma + lane * 8);
  *(float4*)&g[4] = *(const float4*)(gamma + lane * 8 + 4);
  *(float4*)&b[0] = *(const float4*)(beta + lane * 8);
  *(float4*)&b[4] = *(const float4*)(beta + lane * 8 + 4);
  float sum = 0.f, sq = 0.f;
#pragma unroll
  for (int i = 0; i < 8; ++i) { sum += f[i]; sq += f[i] * f[i]; }
#pragma unroll
  for (int off = 1; off < 64; off <<= 1) {
    sum += __shfl_xor(sum, off, 64);
    sq  += __shfl_xor(sq, off, 64);
  }
  float mean = sum * (1.0f / DIMD);
  float var = sq * (1.0f / DIMD) - mean * mean;
  float rstd = rsqrtf(var + 1e-6f);
  union { uint4 v; u16 s[8]; } uo;
#pragma unroll
  for (int i = 0; i < 8; ++i)
    uo.s[i] = f2bf((f[i] - mean) * rstd * g[i] + b[i]);
  *(uint4*)(xn + (size_t)row * DIMD + lane * 8) = uo.v;
}

// ------- QKV GEMM v3: 128x128, counted-vmcnt double-buffered K-loop --------
// Per K-step: BARRIER; stage(k+1)->buf[(k+1)&1]; vmcnt(8); BARRIER;
// compute(k)<-buf[k&1]. stage(k)'s DMA (8/wave) hides under compute(k-1)
// instead of being drained by __syncthreads' implicit vmcnt(0) (m233 stall).
// part = bn>>2 block-uniform: 0->q (scaled), 1->k, 2->v^T (b64-packed).
__global__ __launch_bounds__(256) void qkv_gemm(
    const u16* __restrict__ A, const u16* __restrict__ Bm,
    u16* __restrict__ qo, u16* __restrict__ ko, u16* __restrict__ vto) {
  __shared__ __align__(16) u16 la[2][128 * 64];   // 2 x 16 KB
  __shared__ __align__(16) u16 lb[2][128 * 64];   // 2 x 16 KB
  const int K = DIMD;
  int tid = threadIdx.x;
  int bm = blockIdx.x, bn = blockIdx.y;
  int wid = tid >> 6, lane = tid & 63, lm = lane & 15, quad = lane >> 4;
  int wm = wid >> 1, wn = wid & 1;
  int lsw = lm & 7;
  int part = bn >> 2;  // block-uniform
  f32x4 acc[4][4] = {};
  const u16* Ab = A + (size_t)(bm * 128) * K;
  const u16* Bb = Bm + (size_t)(bn * 128) * K;
  int cb_row = lane >> 3, cb_sub = lane & 7;
  int xsrc = (cb_sub ^ cb_row) * 8;   // swizzled source chunk offset

  auto stage = [&](int ks) {
    int bsel = ks & 1, k0 = ks * 64;
#pragma unroll
    for (int r = 0; r < 4; ++r) {
      int seg = wid * 4 + r;
      int row = seg * 8 + cb_row;
      size_t goff = (size_t)row * K + k0 + xsrc;
      gll16(Ab + goff, &la[bsel][seg * 512]);
      gll16(Bb + goff, &lb[bsel][seg * 512]);
    }
  };

  stage(0);
  for (int ks = 0; ks < 8; ++ks) {
    BARRIER();                       // compute(ks-1) finished by all waves
    if (ks < 7) { stage(ks + 1); WAITV(8); } else { WAITV(0); }
    BARRIER();                       // stage(ks) landed collectively
    int bsel = ks & 1;
#pragma unroll
    for (int h = 0; h < 2; ++h) {
      bf16x8 af[4], bfr[4];
#pragma unroll
      for (int i = 0; i < 4; ++i)
        af[i] = *(const bf16x8*)&la[bsel][(wm * 64 + i * 16 + lm) * 64 + (((h * 4 + quad) ^ lsw) * 8)];
#pragma unroll
      for (int j = 0; j < 4; ++j)
        bfr[j] = *(const bf16x8*)&lb[bsel][(wn * 64 + j * 16 + lm) * 64 + (((h * 4 + quad) ^ lsw) * 8)];
      if (part == 2) {
#pragma unroll
        for (int i = 0; i < 4; ++i)
#pragma unroll
          for (int j = 0; j < 4; ++j)
            acc[i][j] = __builtin_amdgcn_mfma_f32_16x16x32_bf16(af[i], bfr[j], acc[i][j], 0, 0, 0);
      } else {
        // swapped operands: acc regs hold 4 consecutive output cols
#pragma unroll
        for (int i = 0; i < 4; ++i)
#pragma unroll
          for (int j = 0; j < 4; ++j)
            acc[i][j] = __builtin_amdgcn_mfma_f32_16x16x32_bf16(bfr[j], af[i], acc[i][j], 0, 0, 0);
      }
    }
  }
  if (part == 2) {
#pragma unroll
    for (int i = 0; i < 4; ++i)
#pragma unroll
      for (int j = 0; j < 4; ++j) {
        int col = bn * 128 + wn * 64 + j * 16 + lm;
        int rem = col & 511, h = rem >> 6, d = rem & 63;
        int rg = bm * 128 + wm * 64 + i * 16 + quad * 4;
        int b = rg >> 11, nn = rg & 2047;
        union { unsigned long long ll; u16 s4[4]; } pk;
#pragma unroll
        for (int r = 0; r < 4; ++r) pk.s4[r] = f2bf(acc[i][j][r]);
        *(unsigned long long*)&vto[((size_t)(b * NH + h) * DH + d) * SEQN + nn] = pk.ll;
      }
  } else {
    u16* dst = part ? ko : qo;
    float sc = part ? 1.0f : QSCALE;
#pragma unroll
    for (int i = 0; i < 4; ++i)
#pragma unroll
      for (int j = 0; j < 4; ++j) {
        int rg = bm * 128 + wm * 64 + i * 16 + lm;   // token row
        int b = rg >> 11, nn = rg & 2047;
        int col = bn * 128 + wn * 64 + j * 16 + quad * 4;  // 4 consecutive cols
        int rem = col & 511, hh = rem >> 6, d = rem & 63;
        union { unsigned long long ll; __bf16 h4[4]; } pk;
#pragma unroll
        for (int r = 0; r < 4; ++r) pk.h4[r] = (__bf16)(acc[i][j][r] * sc);
        *(unsigned long long*)&dst[((size_t)(b * NH + hh) * SEQN + nn) * DH + d] = pk.ll;
      }
  }
}

// -------- Flash attention v10 (round-4 best, verbatim): 64 Q-rows/wave -----
__global__ __launch_bounds__(256, 2) void attn_kernel(
    const u16* __restrict__ q, const u16* __restrict__ k,
    const u16* __restrict__ vt, u16* __restrict__ att) {
  __shared__ __align__(16) u16 kt[2][64 * 64];    // 2 x 8 KB, chunk-swizzled
  __shared__ __align__(16) u16 vtt[2][64 * 64];   // 2 x 8 KB, chunk-swizzled
  int bh = blockIdx.x;
  int wid = threadIdx.x >> 6, lane = threadIdx.x & 63;
  int l31 = lane & 31, hi = lane >> 5;
  int qrow0 = blockIdx.y * 256 + wid * 64;
  const u16* qb = q + (size_t)bh * SEQN * DH;
  const u16* kb = k + (size_t)bh * SEQN * DH;
  const u16* vb = vt + (size_t)bh * DH * SEQN;

  int cb_row = lane >> 3, cb_sub = lane & 7;
  int xstage = (cb_sub ^ cb_row) * 8;

  // Q B-fragments: lane holds Q[qrow][d = c*16 + hi*8 + j], c=0..3
  bf16x8 qfA[4], qfB[4];
#pragma unroll
  for (int c = 0; c < 4; ++c) {
    qfA[c] = *(const bf16x8*)(qb + (size_t)(qrow0 + l31) * DH + c * 16 + hi * 8);
    qfB[c] = *(const bf16x8*)(qb + (size_t)(qrow0 + 32 + l31) * DH + c * 16 + hi * 8);
  }

  f32x16 OtA0 = {}, OtA1 = {}, OtB0 = {}, OtB1 = {};
  float lA = 0.f, lB = 0.f;   // per-lane half-sums (keys with bit2 == hi)

  auto stage = [&](int bsel, int j0) {
    if (wid < 2) {
#pragma unroll
      for (int i = 0; i < 4; ++i) {
        int seg = wid * 4 + i;
        int row = seg * 8 + cb_row;
        gll16(kb + (size_t)(j0 + row) * DH + xstage, &kt[bsel][seg * 512]);
      }
    } else {
#pragma unroll
      for (int i = 0; i < 4; ++i) {
        int seg = (wid - 2) * 4 + i;
        int row = seg * 8 + cb_row;   // row = d index
        gll16(vb + (size_t)row * SEQN + j0 + xstage, &vtt[bsel][seg * 512]);
      }
    }
  };

  stage(0, 0);
  for (int t = 0; t < SEQN / 64; ++t) {
    int bsel = t & 1;
    __syncthreads();   // drains stage(bsel) [issued last iter] + orders LDS
    if (t + 1 < SEQN / 64) stage(bsel ^ 1, (t + 1) * 64);

    bf16x8 pbA[4], pbB[4];   // PV B-fragments, kv blocks 0..3 (16 kv each)
    int rsw = l31 & 7;
#pragma unroll
    for (int tb = 0; tb < 2; ++tb) {   // two 32-key tiles
      int row = tb * 32 + l31;
      f32x16 zA = {}, zB = {};
      __builtin_amdgcn_s_setprio(1);
#pragma unroll
      for (int c = 0; c < 4; ++c) {
        bf16x8 kf = *(const bf16x8*)&kt[bsel][row * 64 + (((2 * c + hi) ^ rsw) * 8)];
        zA = __builtin_amdgcn_mfma_f32_32x32x16_bf16(kf, qfA[c], zA, 0, 0, 0);
        zB = __builtin_amdgcn_mfma_f32_32x32x16_bf16(kf, qfB[c], zB, 0, 0, 0);
      }
      __builtin_amdgcn_s_setprio(0);
      float eA[16], eB[16];
#pragma unroll
      for (int r = 0; r < 16; ++r) {
        eA[r] = __builtin_amdgcn_exp2f(zA[r]); lA += eA[r];
        eB[r] = __builtin_amdgcn_exp2f(zB[r]); lB += eB[r];
      }
      pbA[tb * 2 + 0] = mkfrag(eA[0], eA[1], eA[2], eA[3], eA[4], eA[5], eA[6], eA[7]);
      pbA[tb * 2 + 1] = mkfrag(eA[8], eA[9], eA[10], eA[11], eA[12], eA[13], eA[14], eA[15]);
      pbB[tb * 2 + 0] = mkfrag(eB[0], eB[1], eB[2], eB[3], eB[4], eB[5], eB[6], eB[7]);
      pbB[tb * 2 + 1] = mkfrag(eB[8], eB[9], eB[10], eB[11], eB[12], eB[13], eB[14], eB[15]);
    }
    // PV: O[d][qrow] += V^T[d][kv] P[kv][qrow]; each va feeds 4 MFMAs
#pragma unroll
    for (int c = 0; c < 4; ++c) {
      bf16x8 va0 = *(const bf16x8*)&vtt[bsel][l31 * 64 + (((2 * c + hi) ^ rsw) * 8)];
      bf16x8 va1 = *(const bf16x8*)&vtt[bsel][(32 + l31) * 64 + (((2 * c + hi) ^ rsw) * 8)];
      __builtin_amdgcn_s_setprio(1);
      OtA0 = __builtin_amdgcn_mfma_f32_32x32x16_bf16(va0, pbA[c], OtA0, 0, 0, 0);
      OtA1 = __builtin_amdgcn_mfma_f32_32x32x16_bf16(va1, pbA[c], OtA1, 0, 0, 0);
      OtB0 = __builtin_amdgcn_mfma_f32_32x32x16_bf16(va0, pbB[c], OtB0, 0, 0, 0);
      OtB1 = __builtin_amdgcn_mfma_f32_32x32x16_bf16(va1, pbB[c], OtB1, 0, 0, 0);
      __builtin_amdgcn_s_setprio(0);
    }
  }
  int b = bh >> 3, h = bh & 7;
  float lAf = lA + __shfl_xor(lA, 32, 64);
  float lBf = lB + __shfl_xor(lB, 32, 64);
  float invA = __builtin_amdgcn_rcpf(lAf);
  float invB = __builtin_amdgcn_rcpf(lBf);
  size_t rowA = ((size_t)(b * SEQN + qrow0 + l31)) * DIMD + h * DH;
  size_t rowB = ((size_t)(b * SEQN + qrow0 + 32 + l31)) * DIMD + h * DH;
#pragma unroll
  for (int rb = 0; rb < 4; ++rb) {
    union { unsigned long long ll; __bf16 h4[4]; } a0, a1, b0, b1;
#pragma unroll
    for (int rr = 0; rr < 4; ++rr) {
      a0.h4[rr] = (__bf16)(OtA0[rb * 4 + rr] * invA);
      a1.h4[rr] = (__bf16)(OtA1[rb * 4 + rr] * invA);
      b0.h4[rr] = (__bf16)(OtB0[rb * 4 + rr] * invB);
      b1.h4[rr] = (__bf16)(OtB1[rb * 4 + rr] * invB);
    }
    *(unsigned long long*)&att[rowA + rb * 8 + hi * 4] = a0.ll;
    *(unsigned long long*)&att[rowA + 32 + rb * 8 + hi * 4] = a1.ll;
    *(unsigned long long*)&att[rowB + rb * 8 + hi * 4] = b0.ll;
    *(unsigned long long*)&att[rowB + 32 + rb * 8 + hi * 4] = b1.ll;
  }
}

// ------- Proj GEMM v3 + bias: counted-vmcnt double-buffered K-loop ---------
__global__ __launch_bounds__(256) void proj_gemm(
    const u16* __restrict__ A, const u16* __restrict__ Bm,
    const float* __restrict__ bias, float* __restrict__ C) {
  __shared__ __align__(16) u16 la[2][128 * 64];
  __shared__ __align__(16) u16 lb[2][128 * 64];
  const int K = DIMD, N = DIMD;
  int tid = threadIdx.x;
  int bm = blockIdx.x, bn = blockIdx.y;
  int wid = tid >> 6, lane = tid & 63, lm = lane & 15, quad = lane >> 4;
  int wm = wid >> 1, wn = wid & 1;
  int lsw = lm & 7;
  f32x4 acc[4][4] = {};
  const u16* Ab = A + (size_t)(bm * 128) * K;
  const u16* Bb = Bm + (size_t)(bn * 128) * K;
  int cb_row = lane >> 3, cb_sub = lane & 7;
  int xsrc = (cb_sub ^ cb_row) * 8;

  auto stage = [&](int ks) {
    int bsel = ks & 1, k0 = ks * 64;
#pragma unroll
    for (int r = 0; r < 4; ++r) {
      int seg = wid * 4 + r;
      int row = seg * 8 + cb_row;
      size_t goff = (size_t)row * K + k0 + xsrc;
      gll16(Ab + goff, &la[bsel][seg * 512]);
      gll16(Bb + goff, &lb[bsel][seg * 512]);
    }
  };

  stage(0);
  for (int ks = 0; ks < 8; ++ks) {
    BARRIER();
    if (ks < 7) { stage(ks + 1); WAITV(8); } else { WAITV(0); }
    BARRIER();
    int bsel = ks & 1;
#pragma unroll
    for (int h = 0; h < 2; ++h) {
      bf16x8 af[4], bfr[4];
#pragma unroll
      for (int i = 0; i < 4; ++i)
        af[i] = *(const bf16x8*)&la[bsel][(wm * 64 + i * 16 + lm) * 64 + (((h * 4 + quad) ^ lsw) * 8)];
#pragma unroll
      for (int j = 0; j < 4; ++j)
        bfr[j] = *(const bf16x8*)&lb[bsel][(wn * 64 + j * 16 + lm) * 64 + (((h * 4 + quad) ^ lsw) * 8)];
#pragma unroll
      for (int i = 0; i < 4; ++i)
#pragma unroll
        for (int j = 0; j < 4; ++j)
          acc[i][j] = __builtin_amdgcn_mfma_f32_16x16x32_bf16(bfr[j], af[i], acc[i][j], 0, 0, 0);
    }
  }
#pragma unroll
  for (int i = 0; i < 4; ++i)
#pragma unroll
    for (int j = 0; j < 4; ++j) {
      int rg = bm * 128 + wm * 64 + i * 16 + lm;           // row
      int col = bn * 128 + wn * 64 + j * 16 + quad * 4;    // 4 consecutive cols
      float4 bv = *(const float4*)(bias + col);
      float4 o;
      o.x = acc[i][j][0] + bv.x; o.y = acc[i][j][1] + bv.y;
      o.z = acc[i][j][2] + bv.z; o.w = acc[i][j][3] + bv.w;
      *(float4*)&C[(size_t)rg * N + col] = o;
    }
}

extern "C" void kernel_launch(void* const* d_in, const int* in_sizes, int n_in,
                              void* d_out, int out_size, void* d_ws, size_t ws_size,
                              hipStream_t stream) {
  const float* x      = (const float*)d_in[0];
  const float* w_qkv  = (const float*)d_in[1];
  const float* w_proj = (const float*)d_in[2];
  const float* b_proj = (const float*)d_in[3];
  const float* gamma  = (const float*)d_in[4];
  const float* beta   = (const float*)d_in[5];
  float* out = (float*)d_out;

  const size_t SZ = (size_t)MROWS * DIMD;  // 8388608 elements
  u16* xn  = (u16*)d_ws;
  u16* q   = xn + SZ;
  u16* kk  = q + SZ;
  u16* vt  = kk + SZ;
  u16* wqb = vt + SZ;                        // 786432 elems bf16
  u16* wpb = wqb + (size_t)3 * DIMD * DIMD;  // 262144 elems bf16
  u16* att = xn;  // reuse: xn dead after qkv_gemm

  const int NQKV = 3 * DIMD * DIMD;   // 786432
  const int NPRJ = DIMD * DIMD;       // 262144
  wcvt2<<<dim3((NQKV + NPRJ) / 2048), dim3(256), 0, stream>>>(
      w_qkv, w_proj, wqb, wpb, NQKV, NPRJ);
  ln_kernel<<<dim3(MROWS / 4), dim3(256), 0, stream>>>(x, gamma, beta, xn);
  qkv_gemm<<<dim3(MROWS / 128, (3 * DIMD) / 128), dim3(256), 0, stream>>>(
      xn, wqb, q, kk, vt);
  attn_kernel<<<dim3(BHN, SEQN / 256), dim3(256), 0, stream>>>(q, kk, vt, att);
  proj_gemm<<<dim3(MROWS / 128, DIMD / 128), dim3(256), 0, stream>>>(
      att, wpb, b_proj, out);
}